// Round 4
// baseline (240.257 us; speedup 1.0000x reference)
//
#include <hip/hip_runtime.h>
#include <cstddef>

// Problem constants
constexpr int Bn  = 16;    // batch
constexpr int CIc = 32;    // in channels
constexpr int COc = 32;    // out channels
constexpr int Kc  = 16;    // kernel width
constexpr int IN  = 8192;  // input length
constexpr int OUTL = 8176; // output length = IN - K

// Tiling
constexpr int O_B  = 16;   // o-positions per block (8176/16 = 511 exact)
constexpr int CCH  = 8;    // channels per cg half per it
constexpr int NPOS = 32;   // staged x positions (31 needed; 32 -> shift-only math, in-bounds: o0+31 <= 8191)
constexpr int BST  = 20;   // padded batch stride in LDS floats (<=2-way read conflicts, free)

// xs[2cg][8cc][32p][20b] = 40960 B, aliased with red[8dg][4jd][16og][20b] = 40960 B
constexpr int SMEM_FLOATS = 2 * CCH * NPOS * BST;  // 10240

__global__ __launch_bounds__(256, 2)
void conv1d_cppn_kernel(const float* __restrict__ x, const float* __restrict__ w,
                        const float* __restrict__ bias, float* __restrict__ out) {
    __shared__ float smem[SMEM_FLOATS];
    float (*xs)[CCH][NPOS][BST] = reinterpret_cast<float (*)[CCH][NPOS][BST]>(smem);
    float (*red)[4][O_B][BST]   = reinterpret_cast<float (*)[4][O_B][BST]>(smem);

    const int tid = threadIdx.x;
    const int og = tid & 15;          // o within tile (fast -> coalesced w loads)
    const int dg = (tid >> 4) & 7;    // 8 d-groups x 4 d each = all 32 d
    const int cg = tid >> 7;          // c-split: cg0 -> c 0..15, cg1 -> c 16..31 (disjoint w => fetch-once)
    const int o0 = blockIdx.x * O_B;
    const int o  = o0 + og;
    const int dbase = dg * 4;

    float acc[4][16];
#pragma unroll
    for (int i = 0; i < 4; ++i)
#pragma unroll
        for (int j = 0; j < 16; ++j) acc[i][j] = 0.f;

    for (int it = 0; it < 2; ++it) {
        __syncthreads();
        // Stage x channels it*16 .. +15 for both cg halves; float4 over p.
        // 2048 float4 per it -> 8 per thread; consecutive lanes -> consecutive addrs.
        for (int idx = tid; idx < 16 * Bn * (NPOS / 4); idx += 256) {
            const int p4 = idx & 7;
            const int t  = idx >> 3;
            const int b  = t & 15;
            const int cl = t >> 4;     // 0..15 local channel
            const float4 v = *reinterpret_cast<const float4*>(
                &x[((size_t)b * CIc + (it * 16 + cl)) * IN + o0 + p4 * 4]);
            float (*prow)[BST] = &xs[cl >> 3][cl & 7][p4 * 4];
            prow[0][b] = v.x;
            prow[1][b] = v.y;
            prow[2][b] = v.z;
            prow[3][b] = v.w;
        }
        __syncthreads();

#pragma unroll 1   // keep code + register pressure bounded (round-3 lesson)
        for (int cc = 0; cc < CCH; ++cc) {
            const int c = it * 16 + cg * 8 + cc;
#pragma unroll
            for (int half = 0; half < 2; ++half) {
                // 8 k-taps of w for 4 d's: 32 live regs (not 64)
                float wvf[4][8];
#pragma unroll
                for (int jd = 0; jd < 4; ++jd) {
                    const float4* wp = reinterpret_cast<const float4*>(
                        w + (((size_t)(dbase + jd) * CIc + c) * OUTL + o) * Kc) + half * 2;
                    const float4 a  = wp[0];
                    const float4 b4 = wp[1];
                    wvf[jd][0] = a.x;  wvf[jd][1] = a.y;  wvf[jd][2] = a.z;  wvf[jd][3] = a.w;
                    wvf[jd][4] = b4.x; wvf[jd][5] = b4.y; wvf[jd][6] = b4.z; wvf[jd][7] = b4.w;
                }
#pragma unroll
                for (int kk = 0; kk < 8; ++kk) {
                    const int k = half * 8 + kk;
                    const float* xrow = &xs[cg][cc][og + k][0];
                    float xv[16];
                    *reinterpret_cast<float4*>(&xv[0])  = *reinterpret_cast<const float4*>(xrow);
                    *reinterpret_cast<float4*>(&xv[4])  = *reinterpret_cast<const float4*>(xrow + 4);
                    *reinterpret_cast<float4*>(&xv[8])  = *reinterpret_cast<const float4*>(xrow + 8);
                    *reinterpret_cast<float4*>(&xv[12]) = *reinterpret_cast<const float4*>(xrow + 12);
#pragma unroll
                    for (int jd = 0; jd < 4; ++jd) {
                        const float wk = wvf[jd][kk];
#pragma unroll
                        for (int jb = 0; jb < 16; ++jb) {
                            acc[jd][jb] += wk * xv[jb];
                        }
                    }
                }
            }
        }
    }

    // Combine cg partials through LDS (aliased with xs; dead after last FMA + barrier).
    __syncthreads();
    if (cg == 1) {
#pragma unroll
        for (int jd = 0; jd < 4; ++jd) {
            float* row = &red[dg][jd][og][0];
#pragma unroll
            for (int q = 0; q < 4; ++q) {
                *reinterpret_cast<float4*>(row + q * 4) =
                    make_float4(acc[jd][q * 4 + 0], acc[jd][q * 4 + 1],
                                acc[jd][q * 4 + 2], acc[jd][q * 4 + 3]);
            }
        }
    }
    __syncthreads();
    if (cg == 0) {
#pragma unroll
        for (int jd = 0; jd < 4; ++jd) {
            const float bv = bias[dbase + jd];
            const float* row = &red[dg][jd][og][0];
#pragma unroll
            for (int jb = 0; jb < 16; ++jb) {
                float v = acc[jd][jb] + row[jb] + bv;
                out[((size_t)jb * COc + (dbase + jd)) * OUTL + o] = v > 0.f ? v : 0.f;
            }
        }
    }
}

extern "C" void kernel_launch(void* const* d_in, const int* in_sizes, int n_in,
                              void* d_out, int out_size, void* d_ws, size_t ws_size,
                              hipStream_t stream) {
    const float* x    = (const float*)d_in[0];
    const float* w    = (const float*)d_in[1];
    const float* bias = (const float*)d_in[2];
    float* out        = (float*)d_out;

    dim3 grid(OUTL / O_B);  // 511
    dim3 block(256);
    hipLaunchKernelGGL(conv1d_cppn_kernel, grid, block, 0, stream, x, w, bias, out);
}

// Round 5
// 135.730 us; speedup vs baseline: 1.7701x; 1.7701x over previous
//
#include <hip/hip_runtime.h>
#include <cstddef>

// Problem constants
constexpr int Bn  = 16;    // batch
constexpr int CIc = 32;    // in channels
constexpr int COc = 32;    // out channels
constexpr int Kc  = 16;    // kernel width
constexpr int IN  = 8192;  // input length
constexpr int OUTL = 8176; // output length = IN - K

// Tiling
constexpr int O_B  = 16;   // o-positions per block (8176/16 = 511 exact)
constexpr int CCH  = 8;    // channels staged per chunk
constexpr int NPOS = 32;   // staged x positions (31 needed; 32 -> shift-only math; o0+31 <= 8191 in bounds)
constexpr int BST  = 20;   // padded batch stride in LDS floats (20p % 32 -> 2-way max on reads: free)
constexpr int NCHUNK = CIc / CCH;  // 4

__global__ __launch_bounds__(256, 3)
void conv1d_cppn_kernel(const float* __restrict__ x, const float* __restrict__ w,
                        const float* __restrict__ bias, float* __restrict__ out) {
    // Ping-pong staging buffers: x transposed as xs[buf][cc][pos][b]
    __shared__ float xs[2][CCH][NPOS][BST];   // 2*8*32*20*4 = 40,960 B -> 3 blocks/CU

    const int tid = threadIdx.x;
    const int og = tid & 15;          // o within tile (fast -> coalesced w loads)
    const int dg = tid >> 4;          // 16 d-groups x 2 d = all 32 d  (round-2 proven mapping)
    const int o0 = blockIdx.x * O_B;
    const int o  = o0 + og;
    const int dbase = dg * 2;

    // Staging decomposition: thread handles fixed (p4, b), channels cl0, cl0+2, cl0+4, cl0+6
    const int sp4 = tid & 7;            // which float4 along p
    const int sb  = (tid >> 3) & 15;    // batch
    const int cl0 = tid >> 7;           // 0 or 1

    float acc[2][16];
#pragma unroll
    for (int i = 0; i < 2; ++i)
#pragma unroll
        for (int j = 0; j < 16; ++j) acc[i][j] = 0.f;

    // Prologue: stage chunk 0 (load + transpose-write), one barrier.
#pragma unroll
    for (int q = 0; q < 4; ++q) {
        const int cl = cl0 + 2 * q;
        const float4 v = *reinterpret_cast<const float4*>(
            &x[((size_t)sb * CIc + cl) * IN + o0 + sp4 * 4]);
        float (*prow)[BST] = &xs[0][cl][sp4 * 4];
        prow[0][sb] = v.x; prow[1][sb] = v.y; prow[2][sb] = v.z; prow[3][sb] = v.w;
    }
    __syncthreads();

    int buf = 0;
    for (int chunk = 0; chunk < NCHUNK; ++chunk) {
        // T14 async split: ISSUE next chunk's global x loads now (latency hides
        // under this chunk's compute); ds_write them after the compute.
        float4 xr[4];
        if (chunk + 1 < NCHUNK) {
            const int c0n = (chunk + 1) * CCH;
#pragma unroll
            for (int q = 0; q < 4; ++q) {
                xr[q] = *reinterpret_cast<const float4*>(
                    &x[((size_t)sb * CIc + c0n + cl0 + 2 * q) * IN + o0 + sp4 * 4]);
            }
        }

        const int c0 = chunk * CCH;
#pragma unroll 2   // round-2 proven: bounded unroll, no reg blowup, fits I-cache
        for (int cc = 0; cc < CCH; ++cc) {
            const int c = c0 + cc;
            float wreg[2][16];
#pragma unroll
            for (int jd = 0; jd < 2; ++jd) {
                const float4* wp = reinterpret_cast<const float4*>(
                    w + (((size_t)(dbase + jd) * CIc + c) * OUTL + o) * Kc);
#pragma unroll
                for (int q = 0; q < 4; ++q) {
                    const float4 v = wp[q];
                    wreg[jd][q * 4 + 0] = v.x;
                    wreg[jd][q * 4 + 1] = v.y;
                    wreg[jd][q * 4 + 2] = v.z;
                    wreg[jd][q * 4 + 3] = v.w;
                }
            }
#pragma unroll
            for (int k = 0; k < Kc; ++k) {
                const float* xrow = &xs[buf][cc][og + k][0];
                float xv[16];
                *reinterpret_cast<float4*>(&xv[0])  = *reinterpret_cast<const float4*>(xrow);
                *reinterpret_cast<float4*>(&xv[4])  = *reinterpret_cast<const float4*>(xrow + 4);
                *reinterpret_cast<float4*>(&xv[8])  = *reinterpret_cast<const float4*>(xrow + 8);
                *reinterpret_cast<float4*>(&xv[12]) = *reinterpret_cast<const float4*>(xrow + 12);
#pragma unroll
                for (int jd = 0; jd < 2; ++jd) {
                    const float wk = wreg[jd][k];
#pragma unroll
                    for (int jb = 0; jb < 16; ++jb) {
                        acc[jd][jb] += wk * xv[jb];
                    }
                }
            }
        }

        // Write the prefetched chunk into the other buffer (disjoint from the
        // buffer other waves are still computing on), then ONE barrier.
        if (chunk + 1 < NCHUNK) {
#pragma unroll
            for (int q = 0; q < 4; ++q) {
                const int cl = cl0 + 2 * q;
                float (*prow)[BST] = &xs[buf ^ 1][cl][sp4 * 4];
                prow[0][sb] = xr[q].x; prow[1][sb] = xr[q].y;
                prow[2][sb] = xr[q].z; prow[3][sb] = xr[q].w;
            }
            __syncthreads();
        }
        buf ^= 1;
    }

    // Epilogue: bias + relu, coalesced over o (consecutive lanes -> consecutive o)
#pragma unroll
    for (int jd = 0; jd < 2; ++jd) {
        const float bv = bias[dbase + jd];
#pragma unroll
        for (int jb = 0; jb < 16; ++jb) {
            float v = acc[jd][jb] + bv;
            out[((size_t)jb * COc + (dbase + jd)) * OUTL + o] = v > 0.f ? v : 0.f;
        }
    }
}

extern "C" void kernel_launch(void* const* d_in, const int* in_sizes, int n_in,
                              void* d_out, int out_size, void* d_ws, size_t ws_size,
                              hipStream_t stream) {
    const float* x    = (const float*)d_in[0];
    const float* w    = (const float*)d_in[1];
    const float* bias = (const float*)d_in[2];
    float* out        = (float*)d_out;

    dim3 grid(OUTL / O_B);  // 511
    dim3 block(256);
    hipLaunchKernelGGL(conv1d_cppn_kernel, grid, block, 0, stream, x, w, bias, out);
}